// Round 7
// baseline (234.342 us; speedup 1.0000x reference)
//
#include <hip/hip_runtime.h>

#define SIGMA_INV 1.0e4f          // 1/SIGMA
#define GAMMA_INV 1.0e4f          // 1/GAMMA
#define ZNEAR 1.0f
#define ZFAR 100.0f
#define EPSV 1e-10f

constexpr int KF = 8;
constexpr int NPIX = 4 * 512 * 512;
constexpr int NPIX4 = NPIX / 4;
constexpr int NFACES = 200000;
// Dropped-slot relative weight <= e^LOG_CUT; worst-case amplification
// (prob ratio ~150 x normalize ~32x) -> ~5e-4, under the 3.9e-3 baseline.
#define LOG_CUT (-16.0f)
#define ZWIN (16.0f / GAMMA_INV)
// delta = exp(-zmax*1e4) < e^-100 ~ 0 when zmax > 0.01: single-survivor
// pixels then have rgb == n exactly (prob cancels) -> skip dists + exps.
#define ZMAX_SAFE 0.01f

// Native vector types for inline-asm register tuples (HIP's int4/float4 are
// structs -> not valid asm "v" tuple operands).
typedef int      i32x4 __attribute__((ext_vector_type(4)));
typedef float    f32x4 __attribute__((ext_vector_type(4)));
typedef unsigned u32x4 __attribute__((ext_vector_type(4)));
typedef float    f32x2 __attribute__((ext_vector_type(2), aligned(4)));

// ---------------------------------------------------------------------------
// Kernel 1: pack the 3 vertex normals of each face into ONE uint4 (16 B).
// 9 components x 14-bit fixed point. Table = 3.2 MB -> L2-resident.
// ---------------------------------------------------------------------------
__global__ __launch_bounds__(256) void pack_face_normals14(
    const int*   __restrict__ faces,   // (F,3)
    const float* __restrict__ vnorm,   // (V,3)
    uint4*       __restrict__ fn,      // (F) packed
    int F)
{
    const int f = blockIdx.x * blockDim.x + threadIdx.x;
    if (f >= F) return;
    const int v[3] = { faces[f * 3 + 0], faces[f * 3 + 1], faces[f * 3 + 2] };

    unsigned long long lo = 0ull, hi = 0ull;
    int i = 0;
#pragma unroll
    for (int t = 0; t < 3; ++t) {
#pragma unroll
        for (int c = 0; c < 3; ++c, ++i) {
            const float x = vnorm[(size_t)v[t] * 3 + c];
            const unsigned long long code = (unsigned long long)(unsigned)
                __float2int_rn(fminf(fmaxf(x, -1.0f), 1.0f) * 8191.5f + 8191.5f);
            const int bp = 14 * i;
            if (bp < 64) {
                lo |= code << bp;
                if (bp > 50) hi |= code >> (64 - bp);
            } else {
                hi |= code << (bp - 64);
            }
        }
    }
    uint4 q;
    q.x = (unsigned)(lo & 0xFFFFFFFFull);
    q.y = (unsigned)(lo >> 32);
    q.z = (unsigned)(hi & 0xFFFFFFFFull);
    q.w = (unsigned)(hi >> 32);
    fn[f] = q;
}

__device__ __forceinline__ float dec14(const unsigned* w, int i) {
    const int bp = 14 * i;
    const int j = bp >> 5;
    const int off = bp & 31;
    unsigned long long u = (unsigned long long)w[j];
    if (j < 3) u |= (unsigned long long)w[j + 1] << 32;
    const unsigned code = (unsigned)(u >> off) & 0x3FFFu;
    return fmaf((float)code, 2.0f / 16383.0f, -1.0f);
}

__device__ __forceinline__ void finish_rgb(
    float accx, float accy, float accz, float wtot, float zmax,
    float& o0, float& o1, float& o2)
{
    const float delta = fmaxf(__expf((EPSV - zmax) * GAMMA_INV), EPSV);
    const float inv_denom = 1.0f / (wtot + delta);
    const float r = (accx + delta) * inv_denom;   // bg = (1,1,1)
    const float g = (accy + delta) * inv_denom;
    const float b = (accz + delta) * inv_denom;
    const float nrm = sqrtf(r * r + g * g + b * b);
    const float invn = 1.0f / fmaxf(nrm, 1e-12f);
    o0 = fmaf(r * invn, 0.5f, 0.5f);
    o1 = fmaf(g * invn, 0.5f, 0.5f);
    o2 = fmaf(b * invn, 0.5f, 0.5f);
}

// Survivor-mask for one pixel from its stream registers. Fully inlined ->
// static register indexing only.
__device__ __forceinline__ void mask_px(
    const i32x4& fa, const i32x4& fb, const f32x4& za, const f32x4& zb,
    int& fsel, int& ksel, float& zmax, bool& heavy)
{
    int f[KF] = {fa[0], fa[1], fa[2], fa[3], fb[0], fb[1], fb[2], fb[3]};
    float zv[KF] = {za[0], za[1], za[2], za[3], zb[0], zb[1], zb[2], zb[3]};
    float zinv[KF];
    zmax = EPSV;
#pragma unroll
    for (int k = 0; k < KF; ++k) {
        const float zi = (f[k] >= 0) ? (ZFAR - zv[k]) * (1.0f / (ZFAR - ZNEAR))
                                     : 0.0f;
        zinv[k] = zi;
        zmax = fmaxf(zmax, zi);
    }
    const float zcut = zmax - ZWIN;
    unsigned rem = 0u;
#pragma unroll
    for (int k = 0; k < KF; ++k)
        if (f[k] >= 0 && zinv[k] > zcut) rem |= (1u << k);

    ksel = 0; fsel = 0;
#pragma unroll
    for (int k = KF - 1; k >= 0; --k)
        if (rem & (1u << k)) { ksel = k; fsel = f[k]; }

    const unsigned rem2 = rem & (rem - 1u);
    // heavy: >=2 survivors, delta-sensitive zmax, or no survivor at all.
    heavy = (rem == 0u) || (rem2 != 0u) || (zmax <= ZMAX_SAFE);
}

// Issue one pixel's scattered gathers (fn x4 + bary x2), sc0, NO wait --
// the counted vmcnt pipeline in the caller consumes them later.
__device__ __forceinline__ void issue_gather(
    const unsigned* qp, const float* bp, u32x4& q, f32x2& b)
{
    asm volatile(
        "global_load_dwordx4 %0, %2, off sc0\n\t"
        "global_load_dwordx2 %1, %3, off sc0"
        : "=&v"(q), "=&v"(b)
        : "v"(qp), "v"(bp)
        : "memory");
}

// Light-path shading: single survivor, delta ~ 0 -> rgb == n (prob cancels).
__device__ __forceinline__ void shade_light(
    const u32x4& q, const f32x2& b01, float zmax,
    float& o0, float& o1, float& o2)
{
    unsigned w[4] = { q[0], q[1], q[2], q[3] };
    const float b0 = b01[0];
    const float b1 = b01[1];
    const float b2 = 1.0f - b0 - b1;   // reference normalizes bary to sum=1
    const float nx = b0 * dec14(w, 0) + b1 * dec14(w, 3) + b2 * dec14(w, 6);
    const float ny = b0 * dec14(w, 1) + b1 * dec14(w, 4) + b2 * dec14(w, 7);
    const float nz = b0 * dec14(w, 2) + b1 * dec14(w, 5) + b2 * dec14(w, 8);
    finish_rgb(nx, ny, nz, 1.0f, zmax, o0, o1, o2);
}

// Heavy path (deferred, ~1-2% of pixels): full exact recompute. Re-reads the
// pixel's p2f/zbuf (L2-hot, +~1 MB total fetch) so the counted-vmcnt
// pipeline above never contains compiler-emitted waits.
__device__ void heavy_px(
    int p,
    const int* __restrict__ p2f, const float* __restrict__ bary,
    const float* __restrict__ zbuf, const float* __restrict__ dists,
    const uint4* __restrict__ fn,
    float& o0, float& o1, float& o2)
{
    const int4* pf4 = reinterpret_cast<const int4*>(p2f + (size_t)p * KF);
    int4 fa = pf4[0], fb = pf4[1];
    int f[KF] = {fa.x, fa.y, fa.z, fa.w, fb.x, fb.y, fb.z, fb.w};
    const float4* z4 = reinterpret_cast<const float4*>(zbuf + (size_t)p * KF);
    float4 za = z4[0], zb = z4[1];
    float zv[KF] = {za.x, za.y, za.z, za.w, zb.x, zb.y, zb.z, zb.w};

    float zinv[KF];
    float zmax = EPSV;
#pragma unroll
    for (int k = 0; k < KF; ++k) {
        const float zi = (f[k] >= 0) ? (ZFAR - zv[k]) * (1.0f / (ZFAR - ZNEAR))
                                     : 0.0f;
        zinv[k] = zi;
        zmax = fmaxf(zmax, zi);
    }
    const float zcut = zmax - ZWIN;
    unsigned rem = 0u;
#pragma unroll
    for (int k = 0; k < KF; ++k)
        if (f[k] >= 0 && zinv[k] > zcut) rem |= (1u << k);

    float accx = 0.0f, accy = 0.0f, accz = 0.0f, wtot = 0.0f;
    while (rem) {
        int ks = 0, gs = 0;
        float zs = 0.0f;
#pragma unroll
        for (int k = KF - 1; k >= 0; --k)
            if (rem & (1u << k)) { ks = k; gs = f[k]; zs = zinv[k]; }
        rem &= rem - 1u;

        const size_t s = (size_t)p * KF + (size_t)ks;
        const uint4 q2 = fn[gs];
        const f32x2 bb = *reinterpret_cast<const f32x2*>(bary + s * 3);
        const float dvs = dists[s];

        unsigned w2[4] = { q2.x, q2.y, q2.z, q2.w };
        const float c0 = bb[0];
        const float c1 = bb[1];
        const float c2 = 1.0f - c0 - c1;
        const float mx = c0 * dec14(w2, 0) + c1 * dec14(w2, 3) + c2 * dec14(w2, 6);
        const float my = c0 * dec14(w2, 1) + c1 * dec14(w2, 4) + c2 * dec14(w2, 7);
        const float mz = c0 * dec14(w2, 2) + c1 * dec14(w2, 5) + c2 * dec14(w2, 8);

        const float prob = 1.0f / (1.0f + __expf(dvs * SIGMA_INV));
        const float wgt  = prob * __expf((zs - zmax) * GAMMA_INV);
        wtot += wgt;
        accx = fmaf(wgt, mx, accx);
        accy = fmaf(wgt, my, accy);
        accz = fmaf(wgt, mz, accz);
    }
    finish_rgb(accx, accy, accz, wtot, zmax, o0, o1, o2);
}

// ---------------------------------------------------------------------------
// Kernel 2 (R14): 4 px/thread + counted-vmcnt pipeline. Ledger R9/R12/R13:
// achieved BW tracks total outstanding random lines (R9 ~20 scattered/thread
// -> 2.6 TB/s; R12 ~2 -> 2.0; R13 ~4 at half waves -> 1.85); fetch already
// at the ~114 MB floor (118 observed). So: keep fetch lean, triple sustained
// per-wave MLP. Phase A: 16 stream loads in one sc0 window. Phase B: masks,
// then ALL 8 scattered gathers issued with no wait. Phase C: consume px i
// behind s_waitcnt vmcnt(6/4/2/0) + sched_barrier(0) (rule #18) -- newer
// gathers stay in flight during older pixels' decode. Phase D: heavy pixels
// (~1-2%) deferred to after the drain (they re-read p2f/zbuf from L2), so
// no compiler-emitted vmcnt(0) can break the pipeline. Stores last.
// ---------------------------------------------------------------------------
__global__ __launch_bounds__(256) void normal_shader_q14_pipe4(
    const int*   __restrict__ p2f,    // (N,H,W,K)
    const float* __restrict__ bary,   // (N,H,W,K,3)
    const float* __restrict__ zbuf,   // (N,H,W,K)
    const float* __restrict__ dists,  // (N,H,W,K)
    const uint4* __restrict__ fn,     // (F) packed face normals
    float*       __restrict__ out)    // (N,H,W,3)
{
    const int t = blockIdx.x * blockDim.x + threadIdx.x;
    if (t >= NPIX4) return;
    const int p0 = t;
    const int p1 = t + NPIX4;
    const int p2 = t + 2 * NPIX4;
    const int p3 = t + 3 * NPIX4;

    const int*   pf0 = p2f + (size_t)p0 * KF;
    const float* zz0 = zbuf + (size_t)p0 * KF;
    const int*   pf1 = p2f + (size_t)p1 * KF;
    const float* zz1 = zbuf + (size_t)p1 * KF;
    const int*   pf2 = p2f + (size_t)p2 * KF;
    const float* zz2 = zbuf + (size_t)p2 * KF;
    const int*   pf3 = p2f + (size_t)p3 * KF;
    const float* zz3 = zbuf + (size_t)p3 * KF;

    // ---- phase A: 16 coalesced stream loads, one sc0 window ----
    i32x4 fA0, fB0, fA1, fB1, fA2, fB2, fA3, fB3;
    f32x4 zA0, zB0, zA1, zB1, zA2, zB2, zA3, zB3;
    asm volatile(
        "global_load_dwordx4 %0, %16, off sc0\n\t"
        "global_load_dwordx4 %1, %16, off offset:16 sc0\n\t"
        "global_load_dwordx4 %2, %17, off sc0\n\t"
        "global_load_dwordx4 %3, %17, off offset:16 sc0\n\t"
        "global_load_dwordx4 %4, %18, off sc0\n\t"
        "global_load_dwordx4 %5, %18, off offset:16 sc0\n\t"
        "global_load_dwordx4 %6, %19, off sc0\n\t"
        "global_load_dwordx4 %7, %19, off offset:16 sc0\n\t"
        "global_load_dwordx4 %8, %20, off sc0\n\t"
        "global_load_dwordx4 %9, %20, off offset:16 sc0\n\t"
        "global_load_dwordx4 %10, %21, off sc0\n\t"
        "global_load_dwordx4 %11, %21, off offset:16 sc0\n\t"
        "global_load_dwordx4 %12, %22, off sc0\n\t"
        "global_load_dwordx4 %13, %22, off offset:16 sc0\n\t"
        "global_load_dwordx4 %14, %23, off sc0\n\t"
        "global_load_dwordx4 %15, %23, off offset:16 sc0\n\t"
        "s_waitcnt vmcnt(0)"
        : "=&v"(fA0), "=&v"(fB0), "=&v"(zA0), "=&v"(zB0),
          "=&v"(fA1), "=&v"(fB1), "=&v"(zA1), "=&v"(zB1),
          "=&v"(fA2), "=&v"(fB2), "=&v"(zA2), "=&v"(zB2),
          "=&v"(fA3), "=&v"(fB3), "=&v"(zA3), "=&v"(zB3)
        : "v"(pf0), "v"(zz0), "v"(pf1), "v"(zz1),
          "v"(pf2), "v"(zz2), "v"(pf3), "v"(zz3)
        : "memory");

    // ---- masks ----
    int fs0, ks0, fs1, ks1, fs2, ks2, fs3, ks3;
    float zm0, zm1, zm2, zm3;
    bool hv0, hv1, hv2, hv3;
    mask_px(fA0, fB0, zA0, zB0, fs0, ks0, zm0, hv0);
    mask_px(fA1, fB1, zA1, zB1, fs1, ks1, zm1, hv1);
    mask_px(fA2, fB2, zA2, zB2, fs2, ks2, zm2, hv2);
    mask_px(fA3, fB3, zA3, zB3, fs3, ks3, zm3, hv3);

    // ---- phase B: issue ALL 8 scattered gathers, no wait ----
    u32x4 g0, g1, g2, g3;
    f32x2 c0, c1, c2, c3;
    issue_gather(reinterpret_cast<const unsigned*>(fn + fs0),
                 bary + ((size_t)p0 * KF + (size_t)ks0) * 3, g0, c0);
    issue_gather(reinterpret_cast<const unsigned*>(fn + fs1),
                 bary + ((size_t)p1 * KF + (size_t)ks1) * 3, g1, c1);
    issue_gather(reinterpret_cast<const unsigned*>(fn + fs2),
                 bary + ((size_t)p2 * KF + (size_t)ks2) * 3, g2, c2);
    issue_gather(reinterpret_cast<const unsigned*>(fn + fs3),
                 bary + ((size_t)p3 * KF + (size_t)ks3) * 3, g3, c3);

    // ---- phase C: counted-vmcnt consumption (oldest first) ----
    float o00, o01, o02, o10, o11, o12, o20, o21, o22, o30, o31, o32;

    asm volatile("s_waitcnt vmcnt(6)" ::: "memory");
    __builtin_amdgcn_sched_barrier(0);
    shade_light(g0, c0, zm0, o00, o01, o02);

    asm volatile("s_waitcnt vmcnt(4)" ::: "memory");
    __builtin_amdgcn_sched_barrier(0);
    shade_light(g1, c1, zm1, o10, o11, o12);

    asm volatile("s_waitcnt vmcnt(2)" ::: "memory");
    __builtin_amdgcn_sched_barrier(0);
    shade_light(g2, c2, zm2, o20, o21, o22);

    asm volatile("s_waitcnt vmcnt(0)" ::: "memory");
    __builtin_amdgcn_sched_barrier(0);
    shade_light(g3, c3, zm3, o30, o31, o32);

    // ---- phase D: deferred heavy pixels (pipeline already drained) ----
    if (hv0) heavy_px(p0, p2f, bary, zbuf, dists, fn, o00, o01, o02);
    if (hv1) heavy_px(p1, p2f, bary, zbuf, dists, fn, o10, o11, o12);
    if (hv2) heavy_px(p2, p2f, bary, zbuf, dists, fn, o20, o21, o22);
    if (hv3) heavy_px(p3, p2f, bary, zbuf, dists, fn, o30, o31, o32);

    // ---- phase E: stores ----
    float* q0p = out + (size_t)p0 * 3;
    q0p[0] = o00; q0p[1] = o01; q0p[2] = o02;
    float* q1p = out + (size_t)p1 * 3;
    q1p[0] = o10; q1p[1] = o11; q1p[2] = o12;
    float* q2p = out + (size_t)p2 * 3;
    q2p[0] = o20; q2p[1] = o21; q2p[2] = o22;
    float* q3p = out + (size_t)p3 * 3;
    q3p[0] = o30; q3p[1] = o31; q3p[2] = o32;
}

// ---------------------------------------------------------------------------
// Fallback (R1 kernel) in case d_ws is too small for the 3.2 MB table.
// ---------------------------------------------------------------------------
__global__ __launch_bounds__(256) void normal_shader_direct(
    const int*   __restrict__ p2f,
    const float* __restrict__ bary,
    const float* __restrict__ zbuf,
    const float* __restrict__ dists,
    const float* __restrict__ vnorm,
    const int*   __restrict__ faces,
    float*       __restrict__ out)
{
    const int p = blockIdx.x * blockDim.x + threadIdx.x;
    if (p >= NPIX) return;

    const int4* pf4 = reinterpret_cast<const int4*>(p2f + (size_t)p * KF);
    int4 fa = pf4[0], fb = pf4[1];
    int f[KF] = {fa.x, fa.y, fa.z, fa.w, fb.x, fb.y, fb.z, fb.w};

    const float4* z4 = reinterpret_cast<const float4*>(zbuf + (size_t)p * KF);
    float4 za = z4[0], zb = z4[1];
    float zv[KF] = {za.x, za.y, za.z, za.w, zb.x, zb.y, zb.z, zb.w};

    const float4* d4 = reinterpret_cast<const float4*>(dists + (size_t)p * KF);
    float4 da = d4[0], db = d4[1];
    float dv[KF] = {da.x, da.y, da.z, da.w, db.x, db.y, db.z, db.w};

    const float4* b4 = reinterpret_cast<const float4*>(bary + (size_t)p * KF * 3);
    float bc[KF * 3];
#pragma unroll
    for (int i = 0; i < 6; ++i) {
        float4 t = b4[i];
        bc[4 * i + 0] = t.x; bc[4 * i + 1] = t.y;
        bc[4 * i + 2] = t.z; bc[4 * i + 3] = t.w;
    }

    float zinv[KF], prob[KF];
    float zmax = EPSV;
#pragma unroll
    for (int k = 0; k < KF; ++k) {
        const bool m = f[k] >= 0;
        const float zi = m ? (ZFAR - zv[k]) * (1.0f / (ZFAR - ZNEAR)) : 0.0f;
        const float pr = m ? 1.0f / (1.0f + __expf(dv[k] * SIGMA_INV)) : 0.0f;
        zinv[k] = zi;
        prob[k] = pr;
        zmax = fmaxf(zmax, zi);
    }

    float accx = 0.0f, accy = 0.0f, accz = 0.0f, wtot = 0.0f;
#pragma unroll
    for (int k = 0; k < KF; ++k) {
        const int idx = f[k] < 0 ? 0 : f[k];
        const int i3 = idx * 3;
        const int v0 = faces[i3 + 0];
        const int v1 = faces[i3 + 1];
        const int v2 = faces[i3 + 2];
        const float b0 = bc[k * 3 + 0];
        const float b1 = bc[k * 3 + 1];
        const float b2 = bc[k * 3 + 2];
        const float* n0 = vnorm + (size_t)v0 * 3;
        const float* n1 = vnorm + (size_t)v1 * 3;
        const float* n2 = vnorm + (size_t)v2 * 3;
        const float nx = b0 * n0[0] + b1 * n1[0] + b2 * n2[0];
        const float ny = b0 * n0[1] + b1 * n1[1] + b2 * n2[1];
        const float nz = b0 * n0[2] + b1 * n1[2] + b2 * n2[2];
        const float wgt = prob[k] * __expf((zinv[k] - zmax) * GAMMA_INV);
        wtot += wgt;
        accx = fmaf(wgt, nx, accx);
        accy = fmaf(wgt, ny, accy);
        accz = fmaf(wgt, nz, accz);
    }

    const float delta = fmaxf(__expf((EPSV - zmax) * GAMMA_INV), EPSV);
    const float inv_denom = 1.0f / (wtot + delta);
    const float r = (accx + delta) * inv_denom;
    const float g = (accy + delta) * inv_denom;
    const float b = (accz + delta) * inv_denom;

    const float nrm = sqrtf(r * r + g * g + b * b);
    const float invn = 1.0f / fmaxf(nrm, 1e-12f);

    float* o = out + (size_t)p * 3;
    o[0] = fmaf(r * invn, 0.5f, 0.5f);
    o[1] = fmaf(g * invn, 0.5f, 0.5f);
    o[2] = fmaf(b * invn, 0.5f, 0.5f);
}

extern "C" void kernel_launch(void* const* d_in, const int* in_sizes, int n_in,
                              void* d_out, int out_size, void* d_ws, size_t ws_size,
                              hipStream_t stream) {
    const int*   p2f   = (const int*)d_in[0];
    const float* bary  = (const float*)d_in[1];
    const float* zbuf  = (const float*)d_in[2];
    const float* dists = (const float*)d_in[3];
    const float* vnorm = (const float*)d_in[4];
    const int*   faces = (const int*)d_in[5];
    float* out = (float*)d_out;

    const int threads = 256;
    const size_t fn_bytes = (size_t)NFACES * sizeof(uint4);  // 3.2 MB

    if (ws_size >= fn_bytes) {
        uint4* fn = (uint4*)d_ws;
        pack_face_normals14<<<(NFACES + threads - 1) / threads, threads, 0, stream>>>(
            faces, vnorm, fn, NFACES);
        normal_shader_q14_pipe4<<<(NPIX4 + threads - 1) / threads, threads, 0, stream>>>(
            p2f, bary, zbuf, dists, fn, out);
    } else {
        normal_shader_direct<<<(NPIX + threads - 1) / threads, threads, 0, stream>>>(
            p2f, bary, zbuf, dists, vnorm, faces, out);
    }
}

// Round 8
// 224.687 us; speedup vs baseline: 1.0430x; 1.0430x over previous
//
#include <hip/hip_runtime.h>

#define SIGMA_INV 1.0e4f          // 1/SIGMA
#define GAMMA_INV 1.0e4f          // 1/GAMMA
#define ZNEAR 1.0f
#define ZFAR 100.0f
#define EPSV 1e-10f

constexpr int KF = 8;
constexpr int NPIX = 4 * 512 * 512;
constexpr int NFACES = 200000;
// Dropped-slot relative weight <= e^LOG_CUT; worst-case amplification
// (prob ratio ~150 x normalize ~32x) -> ~5e-4, under the 3.9e-3 baseline.
#define LOG_CUT (-16.0f)
#define ZWIN (16.0f / GAMMA_INV)
// delta = exp(-zmax*1e4) < e^-100 ~ 0 when zmax > 0.01: single-survivor
// pixels then have rgb == n exactly (prob cancels) -> skip dists + exps.
#define ZMAX_SAFE 0.01f

// Native vector types for inline-asm register tuples (HIP's int4/float4 are
// structs -> not valid asm "v" tuple operands).
typedef int      i32x4 __attribute__((ext_vector_type(4)));
typedef float    f32x4 __attribute__((ext_vector_type(4)));
typedef unsigned u32x4 __attribute__((ext_vector_type(4)));
typedef float    f32x2 __attribute__((ext_vector_type(2), aligned(4)));

// ---------------------------------------------------------------------------
// Kernel 1: pack the 3 vertex normals of each face into ONE uint4 (16 B).
// 9 components x 14-bit fixed point. Table = 3.2 MB -> L2-resident.
// ---------------------------------------------------------------------------
__global__ __launch_bounds__(256) void pack_face_normals14(
    const int*   __restrict__ faces,   // (F,3)
    const float* __restrict__ vnorm,   // (V,3)
    uint4*       __restrict__ fn,      // (F) packed
    int F)
{
    const int f = blockIdx.x * blockDim.x + threadIdx.x;
    if (f >= F) return;
    const int v[3] = { faces[f * 3 + 0], faces[f * 3 + 1], faces[f * 3 + 2] };

    unsigned long long lo = 0ull, hi = 0ull;
    int i = 0;
#pragma unroll
    for (int t = 0; t < 3; ++t) {
#pragma unroll
        for (int c = 0; c < 3; ++c, ++i) {
            const float x = vnorm[(size_t)v[t] * 3 + c];
            const unsigned long long code = (unsigned long long)(unsigned)
                __float2int_rn(fminf(fmaxf(x, -1.0f), 1.0f) * 8191.5f + 8191.5f);
            const int bp = 14 * i;
            if (bp < 64) {
                lo |= code << bp;
                if (bp > 50) hi |= code >> (64 - bp);
            } else {
                hi |= code << (bp - 64);
            }
        }
    }
    uint4 q;
    q.x = (unsigned)(lo & 0xFFFFFFFFull);
    q.y = (unsigned)(lo >> 32);
    q.z = (unsigned)(hi & 0xFFFFFFFFull);
    q.w = (unsigned)(hi >> 32);
    fn[f] = q;
}

__device__ __forceinline__ float dec14(const unsigned* w, int i) {
    const int bp = 14 * i;
    const int j = bp >> 5;
    const int off = bp & 31;
    unsigned long long u = (unsigned long long)w[j];
    if (j < 3) u |= (unsigned long long)w[j + 1] << 32;
    const unsigned code = (unsigned)(u >> off) & 0x3FFFu;
    return fmaf((float)code, 2.0f / 16383.0f, -1.0f);
}

// ---------------------------------------------------------------------------
// Kernel 2 (R15): R12 (1px/thread, lean fetch, 16384 waves) + R9's
// dup-address batched gathers. Ledger R9/R12/R13/R14: achieved BW tracks
// scattered-MLP at CONSTANT wave count (trading waves for depth always
// lost); R9's 2.43 TB/s is the only >2 config and used batched dup-addr
// gathers; R12's hidden cost is the heavy path (P(lane)=6% -> ~4 lanes in
// EVERY wave) adding 2-3 serial epochs per wave. Here: ONE 6-load window =
// fn1+bary1 (all lanes) + fn2+bary2+dists1+dists2 where lanes lacking a
// 2nd survivor / not needing dists point at their survivor-1 bary line
// (already in flight -> no HBM fetch inflation, +~6% real lines only).
// Scattered MLP/thread 2 -> 6 at unchanged wave count; heavy epochs fold
// into the same window. Only >=3-survivor lanes (P(wave)~12%) loop.
// ---------------------------------------------------------------------------
__global__ __launch_bounds__(256) void normal_shader_q14_batch6(
    const int*   __restrict__ p2f,    // (N,H,W,K)
    const float* __restrict__ bary,   // (N,H,W,K,3)
    const float* __restrict__ zbuf,   // (N,H,W,K)
    const float* __restrict__ dists,  // (N,H,W,K)
    const uint4* __restrict__ fn,     // (F) packed face normals
    float*       __restrict__ out)    // (N,H,W,3)
{
    const int p = blockIdx.x * blockDim.x + threadIdx.x;
    if (p >= NPIX) return;

    // ---- window 1: coalesced stream loads (p2f + zbuf), sc0 ----
    const int*   pfp = p2f + (size_t)p * KF;
    const float* zp  = zbuf + (size_t)p * KF;

    i32x4 fa, fb;
    f32x4 za, zb;
    asm volatile(
        "global_load_dwordx4 %0, %4, off sc0\n\t"
        "global_load_dwordx4 %1, %4, off offset:16 sc0\n\t"
        "global_load_dwordx4 %2, %5, off sc0\n\t"
        "global_load_dwordx4 %3, %5, off offset:16 sc0\n\t"
        "s_waitcnt vmcnt(0)"
        : "=&v"(fa), "=&v"(fb), "=&v"(za), "=&v"(zb)
        : "v"(pfp), "v"(zp)
        : "memory");

    int f[KF] = {fa[0], fa[1], fa[2], fa[3], fb[0], fb[1], fb[2], fb[3]};
    float zv[KF] = {za[0], za[1], za[2], za[3], zb[0], zb[1], zb[2], zb[3]};

    // ---- z_inv + running max + survivor mask ----
    float zinv[KF];
    float zmax = EPSV;
#pragma unroll
    for (int k = 0; k < KF; ++k) {
        const float zi = (f[k] >= 0) ? (ZFAR - zv[k]) * (1.0f / (ZFAR - ZNEAR))
                                     : 0.0f;
        zinv[k] = zi;
        zmax = fmaxf(zmax, zi);
    }
    const float zcut = zmax - ZWIN;
    unsigned rem = 0u;
#pragma unroll
    for (int k = 0; k < KF; ++k)
        if (f[k] >= 0 && zinv[k] > zcut) rem |= (1u << k);

    // ---- survivors #1 and #2 (unrolled cndmask chains) ----
    int ks1 = 0, fs1 = 0; float zs1 = 0.0f;
#pragma unroll
    for (int k = KF - 1; k >= 0; --k)
        if (rem & (1u << k)) { ks1 = k; fs1 = f[k]; zs1 = zinv[k]; }
    const bool has1 = (rem != 0u);
    const unsigned rem2 = rem & (rem - 1u);

    int ks2 = ks1, fs2 = fs1; float zs2 = zs1;
#pragma unroll
    for (int k = KF - 1; k >= 0; --k)
        if (rem2 & (1u << k)) { ks2 = k; fs2 = f[k]; zs2 = zinv[k]; }
    const bool has2 = (rem2 != 0u);
    unsigned rem3 = rem2 ? (rem2 & (rem2 - 1u)) : 0u;

    // heavy: needs exact weights (2+ survivors or delta-sensitive zmax,
    // which also covers the all-background rem==0 case).
    const bool heavy = has2 || (zmax <= ZMAX_SAFE);

    // ---- addresses (dup-address trick: unneeded loads re-read the
    //      survivor-1 bary line already in flight -> no extra HBM lines) ----
    const size_t sidx1 = (size_t)p * KF + (size_t)ks1;
    const size_t sidx2 = (size_t)p * KF + (size_t)ks2;
    const unsigned* qp1 = reinterpret_cast<const unsigned*>(fn + fs1);
    const float*    bp1 = bary + sidx1 * 3;
    const unsigned* qp2 = has2 ? reinterpret_cast<const unsigned*>(fn + fs2) : qp1;
    const float*    bp2 = has2 ? bary + sidx2 * 3 : bp1;
    const float*    dp1 = heavy ? dists + sidx1 : bp1;
    const float*    dp2 = has2  ? dists + sidx2 : bp1;

    // ---- window 2: 6 scattered loads, ONE wait ----
    u32x4 q1, q2;
    f32x2 b1, b2;
    float d1, d2;
    asm volatile(
        "global_load_dwordx4 %0, %6, off sc0\n\t"
        "global_load_dwordx2 %1, %7, off sc0\n\t"
        "global_load_dwordx4 %2, %8, off sc0\n\t"
        "global_load_dwordx2 %3, %9, off sc0\n\t"
        "global_load_dword %4, %10, off sc0\n\t"
        "global_load_dword %5, %11, off sc0\n\t"
        "s_waitcnt vmcnt(0)"
        : "=&v"(q1), "=&v"(b1), "=&v"(q2), "=&v"(b2), "=&v"(d1), "=&v"(d2)
        : "v"(qp1), "v"(bp1), "v"(qp2), "v"(bp2), "v"(dp1), "v"(dp2)
        : "memory");

    // ---- decode both normals (dup decode harmless) ----
    unsigned w1[4] = { q1[0], q1[1], q1[2], q1[3] };
    const float a0 = b1[0], a1 = b1[1], a2 = 1.0f - a0 - a1;
    const float n1x = a0 * dec14(w1, 0) + a1 * dec14(w1, 3) + a2 * dec14(w1, 6);
    const float n1y = a0 * dec14(w1, 1) + a1 * dec14(w1, 4) + a2 * dec14(w1, 7);
    const float n1z = a0 * dec14(w1, 2) + a1 * dec14(w1, 5) + a2 * dec14(w1, 8);

    unsigned w2[4] = { q2[0], q2[1], q2[2], q2[3] };
    const float c0 = b2[0], c1 = b2[1], c2 = 1.0f - c0 - c1;
    const float n2x = c0 * dec14(w2, 0) + c1 * dec14(w2, 3) + c2 * dec14(w2, 6);
    const float n2y = c0 * dec14(w2, 1) + c1 * dec14(w2, 4) + c2 * dec14(w2, 7);
    const float n2z = c0 * dec14(w2, 2) + c1 * dec14(w2, 5) + c2 * dec14(w2, 8);

    // ---- accumulate ----
    float accx, accy, accz, wtot;
    if (!heavy) {
        // exactly 1 survivor, delta ~ 0: rgb == n (prob cancels).
        accx = n1x; accy = n1y; accz = n1z; wtot = has1 ? 1.0f : 0.0f;
    } else {
        // exact weights. d1 real for heavy lanes; d2 real when has2.
        const float g1 = has1 ? (1.0f / (1.0f + __expf(d1 * SIGMA_INV)))
                                  * __expf((zs1 - zmax) * GAMMA_INV)
                              : 0.0f;
        const float g2 = has2 ? (1.0f / (1.0f + __expf(d2 * SIGMA_INV)))
                                  * __expf((zs2 - zmax) * GAMMA_INV)
                              : 0.0f;
        wtot = g1 + g2;
        accx = g1 * n1x + g2 * n2x;
        accy = g1 * n1y + g2 * n2y;
        accz = g1 * n1z + g2 * n2z;

        // rare tail: >=3 survivors (P(lane)~0.2%, P(wave)~12%).
        while (rem3) {
            int ks = 0, gs = 0;
            float zs = 0.0f;
#pragma unroll
            for (int k = KF - 1; k >= 0; --k)
                if (rem3 & (1u << k)) { ks = k; gs = f[k]; zs = zinv[k]; }
            rem3 &= rem3 - 1u;

            const size_t s = (size_t)p * KF + (size_t)ks;
            const uint4 qt = fn[gs];
            const f32x2 bb = *reinterpret_cast<const f32x2*>(bary + s * 3);
            const float dvs = dists[s];

            unsigned wt[4] = { qt.x, qt.y, qt.z, qt.w };
            const float e0 = bb[0];
            const float e1 = bb[1];
            const float e2 = 1.0f - e0 - e1;
            const float mx = e0 * dec14(wt, 0) + e1 * dec14(wt, 3) + e2 * dec14(wt, 6);
            const float my = e0 * dec14(wt, 1) + e1 * dec14(wt, 4) + e2 * dec14(wt, 7);
            const float mz = e0 * dec14(wt, 2) + e1 * dec14(wt, 5) + e2 * dec14(wt, 8);

            const float prob = 1.0f / (1.0f + __expf(dvs * SIGMA_INV));
            const float wgt  = prob * __expf((zs - zmax) * GAMMA_INV);
            wtot += wgt;
            accx = fmaf(wgt, mx, accx);
            accy = fmaf(wgt, my, accy);
            accz = fmaf(wgt, mz, accz);
        }
    }

    // ---- epilogue ----
    const float delta = fmaxf(__expf((EPSV - zmax) * GAMMA_INV), EPSV);
    const float inv_denom = 1.0f / (wtot + delta);
    const float r = (accx + delta) * inv_denom;   // bg = (1,1,1)
    const float g = (accy + delta) * inv_denom;
    const float b = (accz + delta) * inv_denom;

    const float nrm = sqrtf(r * r + g * g + b * b);
    const float invn = 1.0f / fmaxf(nrm, 1e-12f);

    float* o = out + (size_t)p * 3;
    o[0] = fmaf(r * invn, 0.5f, 0.5f);
    o[1] = fmaf(g * invn, 0.5f, 0.5f);
    o[2] = fmaf(b * invn, 0.5f, 0.5f);
}

// ---------------------------------------------------------------------------
// Fallback (R1 kernel) in case d_ws is too small for the 3.2 MB table.
// ---------------------------------------------------------------------------
__global__ __launch_bounds__(256) void normal_shader_direct(
    const int*   __restrict__ p2f,
    const float* __restrict__ bary,
    const float* __restrict__ zbuf,
    const float* __restrict__ dists,
    const float* __restrict__ vnorm,
    const int*   __restrict__ faces,
    float*       __restrict__ out)
{
    const int p = blockIdx.x * blockDim.x + threadIdx.x;
    if (p >= NPIX) return;

    const int4* pf4 = reinterpret_cast<const int4*>(p2f + (size_t)p * KF);
    int4 fa = pf4[0], fb = pf4[1];
    int f[KF] = {fa.x, fa.y, fa.z, fa.w, fb.x, fb.y, fb.z, fb.w};

    const float4* z4 = reinterpret_cast<const float4*>(zbuf + (size_t)p * KF);
    float4 za = z4[0], zb = z4[1];
    float zv[KF] = {za.x, za.y, za.z, za.w, zb.x, zb.y, zb.z, zb.w};

    const float4* d4 = reinterpret_cast<const float4*>(dists + (size_t)p * KF);
    float4 da = d4[0], db = d4[1];
    float dv[KF] = {da.x, da.y, da.z, da.w, db.x, db.y, db.z, db.w};

    const float4* b4 = reinterpret_cast<const float4*>(bary + (size_t)p * KF * 3);
    float bc[KF * 3];
#pragma unroll
    for (int i = 0; i < 6; ++i) {
        float4 t = b4[i];
        bc[4 * i + 0] = t.x; bc[4 * i + 1] = t.y;
        bc[4 * i + 2] = t.z; bc[4 * i + 3] = t.w;
    }

    float zinv[KF], prob[KF];
    float zmax = EPSV;
#pragma unroll
    for (int k = 0; k < KF; ++k) {
        const bool m = f[k] >= 0;
        const float zi = m ? (ZFAR - zv[k]) * (1.0f / (ZFAR - ZNEAR)) : 0.0f;
        const float pr = m ? 1.0f / (1.0f + __expf(dv[k] * SIGMA_INV)) : 0.0f;
        zinv[k] = zi;
        prob[k] = pr;
        zmax = fmaxf(zmax, zi);
    }

    float accx = 0.0f, accy = 0.0f, accz = 0.0f, wtot = 0.0f;
#pragma unroll
    for (int k = 0; k < KF; ++k) {
        const int idx = f[k] < 0 ? 0 : f[k];
        const int i3 = idx * 3;
        const int v0 = faces[i3 + 0];
        const int v1 = faces[i3 + 1];
        const int v2 = faces[i3 + 2];
        const float b0 = bc[k * 3 + 0];
        const float b1 = bc[k * 3 + 1];
        const float b2 = bc[k * 3 + 2];
        const float* n0 = vnorm + (size_t)v0 * 3;
        const float* n1 = vnorm + (size_t)v1 * 3;
        const float* n2 = vnorm + (size_t)v2 * 3;
        const float nx = b0 * n0[0] + b1 * n1[0] + b2 * n2[0];
        const float ny = b0 * n0[1] + b1 * n1[1] + b2 * n2[1];
        const float nz = b0 * n0[2] + b1 * n1[2] + b2 * n2[2];
        const float wgt = prob[k] * __expf((zinv[k] - zmax) * GAMMA_INV);
        wtot += wgt;
        accx = fmaf(wgt, nx, accx);
        accy = fmaf(wgt, ny, accy);
        accz = fmaf(wgt, nz, accz);
    }

    const float delta = fmaxf(__expf((EPSV - zmax) * GAMMA_INV), EPSV);
    const float inv_denom = 1.0f / (wtot + delta);
    const float r = (accx + delta) * inv_denom;
    const float g = (accy + delta) * inv_denom;
    const float b = (accz + delta) * inv_denom;

    const float nrm = sqrtf(r * r + g * g + b * b);
    const float invn = 1.0f / fmaxf(nrm, 1e-12f);

    float* o = out + (size_t)p * 3;
    o[0] = fmaf(r * invn, 0.5f, 0.5f);
    o[1] = fmaf(g * invn, 0.5f, 0.5f);
    o[2] = fmaf(b * invn, 0.5f, 0.5f);
}

extern "C" void kernel_launch(void* const* d_in, const int* in_sizes, int n_in,
                              void* d_out, int out_size, void* d_ws, size_t ws_size,
                              hipStream_t stream) {
    const int*   p2f   = (const int*)d_in[0];
    const float* bary  = (const float*)d_in[1];
    const float* zbuf  = (const float*)d_in[2];
    const float* dists = (const float*)d_in[3];
    const float* vnorm = (const float*)d_in[4];
    const int*   faces = (const int*)d_in[5];
    float* out = (float*)d_out;

    const int threads = 256;
    const size_t fn_bytes = (size_t)NFACES * sizeof(uint4);  // 3.2 MB

    if (ws_size >= fn_bytes) {
        uint4* fn = (uint4*)d_ws;
        pack_face_normals14<<<(NFACES + threads - 1) / threads, threads, 0, stream>>>(
            faces, vnorm, fn, NFACES);
        normal_shader_q14_batch6<<<(NPIX + threads - 1) / threads, threads, 0, stream>>>(
            p2f, bary, zbuf, dists, fn, out);
    } else {
        normal_shader_direct<<<(NPIX + threads - 1) / threads, threads, 0, stream>>>(
            p2f, bary, zbuf, dists, vnorm, faces, out);
    }
}